// Round 5
// baseline (196.106 us; speedup 1.0000x reference)
//
#include <hip/hip_runtime.h>

// VQ: z [32,256,32,32] f32, codebook [1024,256] f32
// out: z_q [32,256,32,32] f32 (8388608) then loss scalar f32 (1)
#define NELEM 8388608

typedef __attribute__((ext_vector_type(16))) float f32x16;
typedef unsigned long long ull;

// ---------------------------------------------------------------------------
// prep: codebook -> fp8 e4m3 (scaled x256, exact pow2) in B-fragment-linear
// order for mfma_f32_32x32x16_fp8_fp8, plus exact fp32 norms cn[k].
// frag g = nt*16+ks (512 B): lane L holds cb[nt*32+(L&31)][ks*16+(L>>5)*8+0..7]
__global__ __launch_bounds__(256) void prep_kernel(const float* __restrict__ cb,
                                                   uint2* __restrict__ cbf8,
                                                   float* __restrict__ cn) {
    const int t = threadIdx.x;
    const int gt = blockIdx.x * 256 + t;          // 0..32767
    const int L = gt & 63, g = gt >> 6;           // frag 0..511
    const int nt = g >> 4, ks = g & 15;
    const int code = nt * 32 + (L & 31);
    const int k0 = ks * 16 + (L >> 5) * 8;
    const float* s = cb + code * 256 + k0;
    float v[8];
    #pragma unroll
    for (int j = 0; j < 8; ++j) v[j] = s[j] * 256.0f;
    int lo = 0, hi = 0;
    lo = __builtin_amdgcn_cvt_pk_fp8_f32(v[0], v[1], lo, false);
    lo = __builtin_amdgcn_cvt_pk_fp8_f32(v[2], v[3], lo, true);
    hi = __builtin_amdgcn_cvt_pk_fp8_f32(v[4], v[5], hi, false);
    hi = __builtin_amdgcn_cvt_pk_fp8_f32(v[6], v[7], hi, true);
    uint2 o; o.x = (unsigned)lo; o.y = (unsigned)hi;
    cbf8[g * 64 + L] = o;

    const int w = t >> 6, lane = t & 63;
    #pragma unroll
    for (int cc = 0; cc < 2; ++cc) {
        int cd = blockIdx.x * 8 + w * 2 + cc;
        float4 qv = *(const float4*)(cb + cd * 256 + lane * 4);
        float s2 = qv.x*qv.x + qv.y*qv.y + qv.z*qv.z + qv.w*qv.w;
        #pragma unroll
        for (int off = 32; off; off >>= 1) s2 += __shfl_down(s2, off, 64);
        if (lane == 0) cn[cd] = s2;
    }
}

// ---------------------------------------------------------------------------
// Argmin: grid 512 = 256 pos-groups x 2 codebook-halves. Block 256 thr =
// 4 waves x 32 pos, 512 codes. No LDS, no barriers: A resident in regs,
// B-frags streamed global->reg (L1/L2 hot), 32x32x16 fp8 MFMA.
// dist = cn - 2*dot, packed monotone-uint with code in low 10 bits,
// combined across halves via global atomicMin.
__global__ __launch_bounds__(256, 2) void vq_kernel(
        const float* __restrict__ z, const uint2* __restrict__ cbf8,
        const float* __restrict__ cn, unsigned* __restrict__ keys) {
    const int t = threadIdx.x, w = t >> 6, L = t & 63;
    const int half = blockIdx.x >> 8;             // pairs 256 apart: same XCD
    const int pg = blockIdx.x & 255;
    const int b = pg >> 3, hw0 = (pg & 7) << 7;
    const int m = L & 31, hf = L >> 5;

    // A-frags: wave w owns pos w*32..w*32+31. A[m][k=ks*16+hf*8+j], x16 -> fp8
    ull af[16];
    const float* zb = z + ((size_t)b << 18) + hw0 + w * 32 + m;
    #pragma unroll
    for (int ks = 0; ks < 16; ++ks) {
        const float* sp = zb + ((size_t)(ks * 16 + hf * 8) << 10);
        float v[8];
        #pragma unroll
        for (int j = 0; j < 8; ++j) v[j] = sp[(size_t)j << 10];
        int lo = 0, hi = 0;
        lo = __builtin_amdgcn_cvt_pk_fp8_f32(v[0]*16.f, v[1]*16.f, lo, false);
        lo = __builtin_amdgcn_cvt_pk_fp8_f32(v[2]*16.f, v[3]*16.f, lo, true);
        hi = __builtin_amdgcn_cvt_pk_fp8_f32(v[4]*16.f, v[5]*16.f, hi, false);
        hi = __builtin_amdgcn_cvt_pk_fp8_f32(v[6]*16.f, v[7]*16.f, hi, true);
        af[ks] = ((ull)(unsigned)hi << 32) | (unsigned)lo;
    }

    const int colcode = half * 512 + m;           // this lane's code column base
    float cnreg[16];
    #pragma unroll
    for (int nt = 0; nt < 16; ++nt) cnreg[nt] = cn[colcode + nt * 32];

    unsigned runmin[16];
    #pragma unroll
    for (int r = 0; r < 16; ++r) runmin[r] = 0xFFFFFFFFu;

    const uint2* bp = cbf8 + (size_t)(half * 256) * 64;   // half's 16 tiles
    const float SC = -4.8828125e-4f;              // -2 / (16*256)

    uint2 breg[2][16];
    #pragma unroll
    for (int ks = 0; ks < 16; ++ks) breg[0][ks] = bp[ks * 64 + L];

    for (int nt = 0; nt < 16; ++nt) {
        const int cur = nt & 1;
        if (nt < 15) {
            #pragma unroll
            for (int ks = 0; ks < 16; ++ks)
                breg[cur ^ 1][ks] = bp[((nt + 1) * 16 + ks) * 64 + L];
        }
        f32x16 acc = {0,0,0,0, 0,0,0,0, 0,0,0,0, 0,0,0,0};
        #pragma unroll
        for (int ks = 0; ks < 16; ++ks) {
            ull bb = ((ull)breg[cur][ks].y << 32) | breg[cur][ks].x;
            acc = __builtin_amdgcn_mfma_f32_32x32x16_fp8_fp8(
                      (long long)af[ks], (long long)bb, acc, 0, 0, 0);
        }
        const unsigned kc = (unsigned)(colcode + nt * 32);
        #pragma unroll
        for (int r = 0; r < 16; ++r) {
            float d = fmaf(SC, acc[r], cnreg[nt]);
            unsigned bits = __float_as_uint(d) & ~1023u;
            unsigned mono = (bits & 0x80000000u) ? ~bits : (bits | 0x80000000u);
            unsigned key = (mono & ~1023u) | kc;
            runmin[r] = min(runmin[r], key);
        }
    }

    // cross-lane min over the 32 code columns (xor<32 keeps half-wave)
    #pragma unroll
    for (int r = 0; r < 16; ++r) {
        unsigned v = runmin[r];
        #pragma unroll
        for (int d = 1; d < 32; d <<= 1) {
            unsigned ov = __shfl_xor(v, d, 64);
            v = min(v, ov);
        }
        if (m == 0) {
            int row = (r & 3) + 8 * (r >> 2) + 4 * hf;
            atomicMin(&keys[pg * 128 + w * 32 + row], v);
        }
    }
}

// ---------------------------------------------------------------------------
// Scatter: extract winning codes, gather fp32 codebook rows (coalesced),
// transpose via LDS, write z_q; exact loss = 1.25*mean((q-z)^2).
__global__ __launch_bounds__(256) void scatter_kernel(
        const float* __restrict__ z, const float* __restrict__ cb,
        const unsigned* __restrict__ keys, float* __restrict__ out,
        float* __restrict__ loss) {
    __shared__ float Q[32][257];
    __shared__ int codeS[64];
    __shared__ float wsum[4];
    const int t = threadIdx.x, w = t >> 6, L = t & 63;
    const int n0 = blockIdx.x * 64;
    const int b = n0 >> 10, hw0 = n0 & 1023;

    if (t < 64) codeS[t] = (int)(keys[n0 + t] & 1023u);
    __syncthreads();

    float acc = 0.f;
    const size_t obase = ((size_t)b << 18) + hw0;
    const int pgq = L & 7, cidx = L >> 3;
    #pragma unroll
    for (int ch = 0; ch < 2; ++ch) {
        if (ch) __syncthreads();
        #pragma unroll
        for (int rr = 0; rr < 8; ++rr) {
            int row = w * 8 + rr;
            int code = codeS[ch * 32 + row];
            float4 v = *(const float4*)(cb + ((size_t)code << 8) + (L << 2));
            float* qp = &Q[row][L << 2];
            qp[0] = v.x; qp[1] = v.y; qp[2] = v.z; qp[3] = v.w;
        }
        __syncthreads();
        #pragma unroll
        for (int i = 0; i < 8; ++i) {
            int c = w * 64 + i * 8 + cidx;
            int p0 = pgq * 4;
            float4 qv;
            qv.x = Q[p0 + 0][c]; qv.y = Q[p0 + 1][c];
            qv.z = Q[p0 + 2][c]; qv.w = Q[p0 + 3][c];
            size_t addr = obase + ((size_t)c << 10) + ch * 32 + p0;
            float4 zv = *(const float4*)(z + addr);
            *(float4*)(out + addr) = qv;
            float dx = qv.x - zv.x, dy = qv.y - zv.y;
            float dz2 = qv.z - zv.z, dw = qv.w - zv.w;
            acc += dx * dx + dy * dy + dz2 * dz2 + dw * dw;
        }
    }
    #pragma unroll
    for (int off = 32; off; off >>= 1) acc += __shfl_down(acc, off, 64);
    if (L == 0) wsum[w] = acc;
    __syncthreads();
    if (t == 0)
        atomicAdd(loss, (wsum[0] + wsum[1] + wsum[2] + wsum[3]) * (1.25f / (float)NELEM));
}

// ---------------------------------------------------------------------------
extern "C" void kernel_launch(void* const* d_in, const int* in_sizes, int n_in,
                              void* d_out, int out_size, void* d_ws, size_t ws_size,
                              hipStream_t stream) {
    const float* z  = (const float*)d_in[0];
    const float* cb = (const float*)d_in[1];
    float* out      = (float*)d_out;
    float* cn       = (float*)d_ws;                           // 4 KB
    unsigned* keys  = (unsigned*)((char*)d_ws + 4096);        // 128 KB
    uint2* cbf8     = (uint2*)((char*)d_ws + 4096 + 131072);  // 256 KB
    float* loss     = out + NELEM;

    hipMemsetAsync(loss, 0, sizeof(float), stream);
    hipMemsetAsync(keys, 0xFF, 32768 * sizeof(unsigned), stream);
    prep_kernel<<<128, 256, 0, stream>>>(cb, cbf8, cn);
    vq_kernel<<<512, 256, 0, stream>>>(z, cbf8, cn, keys);
    scatter_kernel<<<512, 256, 0, stream>>>(z, cb, keys, out, loss);
}